// Round 11
// baseline (92.555 us; speedup 1.0000x reference)
//
#include <hip/hip_runtime.h>

typedef int   int4v   __attribute__((ext_vector_type(4)));

#define NB      256
#define NP1     10000
#define KNN     32
#define THREADS 1024
#define NWAVES  (THREADS / 64)
#define HALF_N  (NP1 / 2)        // 5000 nodes per half-block
#define ITEMS_F 10               // staging iterations for full psi
#define ITEMS_H 5                // per-half items (5000/1024 -> 5)
#define GROUPS_H (HALF_N / 8)    // 625 groups of 8 nodes per half
#define NEG_INF -1000000000.0f

// ---------------- kernel 1: fused scores + per-half (m, s) ----------------
__global__ __launch_bounds__(THREADS, 8) void hybrid_scores_kernel(
    const float* __restrict__ query,        // [B,2]
    const float* __restrict__ psi,          // [B,NP1,2]
    const int*   __restrict__ knn,          // [B,NP1,K]
    const int*   __restrict__ mask,         // [B,NP1] (bool pushed as int32)
    const float* __restrict__ cur,          // [B,2]
    const float* __restrict__ allc,         // [B,NP1,2]
    const float* __restrict__ lam_p,        // [1]
    const float* __restrict__ mu_p,         // [1]
    float* __restrict__ out,                // [B,NP1] raw scores
    float2* __restrict__ ws_ms)             // [B*2] per-half (m, s)
{
    __shared__ unsigned s_psi[NP1];         // packed bf16 (y<<16 | x), 40 KB
    __shared__ float    s_sc[HALF_N];       // own-half raw scores, 20 KB
    __shared__ float    red[NWAVES];

    // XCD pairing: both halves of a row land on the same XCD (psi L2 reuse;
    // finalize kernel is matched to the same XCD for L2-hit RMW).
    const int bid  = blockIdx.x;
    const int xcd  = bid & 7;
    const int slot = bid >> 3;              // [0,64)
    const int b    = xcd * 32 + (slot >> 1);
    const int half = slot & 1;

    const int t    = threadIdx.x;
    const int lane = t & 63;
    const int wid  = t >> 6;
    const int nbase = half * HALF_N;

    const float lam = lam_p[0];
    const float mu  = mu_p[0];
    const float qx  = query[2*b],  qy = query[2*b+1];
    const float cx  = cur[2*b],    cy = cur[2*b+1];

    const float2* __restrict__ pb = (const float2*)(psi  + (long)b * NP1 * 2);
    const float2* __restrict__ ab = (const float2*)(allc + (long)b * NP1 * 2);
    const int4v*  __restrict__ kb = (const int4v*)(knn + (long)b * NP1 * KNN);
    const int*    __restrict__ mb = mask + (long)b * NP1;

    // ---- stage FULL psi[b] into LDS (packed bf16) — the only pre-stream work
    #pragma unroll
    for (int i = 0; i < ITEMS_F; ++i) {
        const int n = t + i * THREADS;
        if (n < NP1) {
            const float2 p = pb[n];
            unsigned ux = __float_as_uint(p.x);
            unsigned uy = __float_as_uint(p.y);
            ux = (ux + 0x7FFFu + ((ux >> 16) & 1u)) >> 16;          // bf16 RNE
            uy = (uy + 0x7FFFu + ((uy >> 16) & 1u)) & 0xFFFF0000u;  // bf16 RNE
            s_psi[n] = uy | ux;
        }
    }
    __syncthreads();

    // ---- fused phase A: knn stream + gather-dot + score + writes,
    //      8 lanes per node; group-leader lane finishes the node
    const int gbase = half * GROUPS_H;
    for (int g = gbase + wid; g < gbase + GROUPS_H; g += NWAVES) {
        const int4v id = __builtin_nontemporal_load(&kb[(size_t)g * 64 + lane]);
        const int  n0 = g * 8 + (lane >> 3);

        const unsigned up = s_psi[n0];               // 8-lane broadcast
        const float px = __uint_as_float(up << 16);
        const float py = __uint_as_float(up & 0xFFFF0000u);

        const unsigned u0 = s_psi[id.x];
        const unsigned u1 = s_psi[id.y];
        const unsigned u2 = s_psi[id.z];
        const unsigned u3 = s_psi[id.w];
        const float nsx = __uint_as_float(u0 << 16) + __uint_as_float(u1 << 16)
                        + __uint_as_float(u2 << 16) + __uint_as_float(u3 << 16);
        const float nsy = __uint_as_float(u0 & 0xFFFF0000u) + __uint_as_float(u1 & 0xFFFF0000u)
                        + __uint_as_float(u2 & 0xFFFF0000u) + __uint_as_float(u3 & 0xFFFF0000u);

        float dot = px * nsx + py * nsy;             // partial over 4 neighbors
        dot += __shfl_xor(dot, 1);
        dot += __shfl_xor(dot, 2);
        dot += __shfl_xor(dot, 4);                   // sum over all 32 neighbors

        if ((lane & 7) == 0) {
            // 8 active lanes cover 8 consecutive nodes: allc 64 B, mask 32 B
            const float2 ac = ab[n0];
            const int    mk = mb[n0];
            const float dx = ac.x - cx, dy = ac.y - cy;
            const float dist = sqrtf(dx * dx + dy * dy);
            float v = px * qx + py * qy + lam * dot - mu * dist;
            if (mk != 0) v = NEG_INF;
            out[(long)b * NP1 + n0] = v;             // raw score (L2-resident)
            s_sc[n0 - nbase] = v;                    // for in-block (m,s)
        }
    }
    __syncthreads();

    // ---- half-block max over s_sc
    float m = -INFINITY;
    #pragma unroll
    for (int i = 0; i < ITEMS_H; ++i) {
        const int ln = t + i * THREADS;
        if (ln < HALF_N) m = fmaxf(m, s_sc[ln]);
    }
    #pragma unroll
    for (int off = 32; off > 0; off >>= 1) m = fmaxf(m, __shfl_xor(m, off));
    if (lane == 0) red[wid] = m;
    __syncthreads();
    float M = red[0];
    #pragma unroll
    for (int w = 1; w < NWAVES; ++w) M = fmaxf(M, red[w]);
    __syncthreads();   // red reused below

    // ---- half-block sum of exp(sc - M)
    float s = 0.f;
    #pragma unroll
    for (int i = 0; i < ITEMS_H; ++i) {
        const int ln = t + i * THREADS;
        if (ln < HALF_N) s += __expf(s_sc[ln] - M);
    }
    #pragma unroll
    for (int off = 32; off > 0; off >>= 1) s += __shfl_xor(s, off);
    if (lane == 0) red[wid] = s;
    __syncthreads();
    if (t == 0) {
        float S = 0.f;
        #pragma unroll
        for (int w = 0; w < NWAVES; ++w) S += red[w];
        ws_ms[b * 2 + half] = make_float2(M, S);
    }
}

// ---------------- kernel 2: combine (m,s), subtract lse ----------------
// XCD-matched: row b's raw scores live in XCD (b>>5)'s L2.
#define CHUNK 1250
__global__ __launch_bounds__(THREADS) void hybrid_finalize_kernel(
    float* __restrict__ out, const float2* __restrict__ ws_ms)
{
    const int bid = blockIdx.x;
    const int xcd = bid & 7;
    const int k   = bid >> 3;               // [0,256)
    const int b   = xcd * 32 + (k >> 3);
    const int cnk = k & 7;
    const int t   = threadIdx.x;

    const float2 a = ws_ms[b * 2 + 0];
    const float2 c = ws_ms[b * 2 + 1];
    const float M = fmaxf(a.x, c.x);
    const float S = a.y * __expf(a.x - M) + c.y * __expf(c.x - M);
    const float lse = M + logf(S);

    const long base = (long)b * NP1 + (long)cnk * CHUNK;
    #pragma unroll
    for (int i = 0; i < 2; ++i) {
        const int ln = t + i * THREADS;
        if (ln < CHUNK) {
            const float v = out[base + ln] - lse;
            __builtin_nontemporal_store(v, &out[base + ln]);
        }
    }
}

extern "C" void kernel_launch(void* const* d_in, const int* in_sizes, int n_in,
                              void* d_out, int out_size, void* d_ws, size_t ws_size,
                              hipStream_t stream) {
    const float* query = (const float*)d_in[0];
    const float* psi   = (const float*)d_in[1];
    const int*   knn   = (const int*)d_in[2];
    const int*   mask  = (const int*)d_in[3];
    const float* cur   = (const float*)d_in[4];
    const float* allc  = (const float*)d_in[5];
    const float* lam   = (const float*)d_in[6];
    const float* mu    = (const float*)d_in[7];
    float* out = (float*)d_out;
    float2* ws_ms = (float2*)d_ws;          // 512 float2 = 4 KB

    hybrid_scores_kernel<<<NB * 2, THREADS, 0, stream>>>(
        query, psi, knn, mask, cur, allc, lam, mu, out, ws_ms);
    hybrid_finalize_kernel<<<NB * 8, THREADS, 0, stream>>>(out, ws_ms);
}

// Round 12
// 71.405 us; speedup vs baseline: 1.2962x; 1.2962x over previous
//
#include <hip/hip_runtime.h>

typedef int int4v __attribute__((ext_vector_type(4)));

#define NB      256
#define NP1     10000
#define KNN     32
#define THREADS 1024
#define NWAVES  (THREADS / 64)
#define HALF_N  (NP1 / 2)        // 5000 nodes per half-block
#define ITEMS_H 5                // per-half items (5000/1024 -> 5)
#define GROUPS_H (HALF_N / 8)    // 625 groups of 8 nodes per half
#define NEG_INF -1000000000.0f

// ---------------- kernel 1: scores + per-half (m, s) ----------------
__global__ __launch_bounds__(THREADS, 8) void hybrid_scores_kernel(
    const float* __restrict__ query,        // [B,2]
    const float* __restrict__ psi,          // [B,NP1,2]
    const int*   __restrict__ knn,          // [B,NP1,K]
    const int*   __restrict__ mask,         // [B,NP1] (bool pushed as int32)
    const float* __restrict__ cur,          // [B,2]
    const float* __restrict__ allc,         // [B,NP1,2]
    const float* __restrict__ lam_p,        // [1]
    const float* __restrict__ mu_p,         // [1]
    float* __restrict__ out,                // [B,NP1] raw scores
    float2* __restrict__ ws_ms)             // [B*2] per-half (m, s)
{
    __shared__ unsigned s_psi[NP1];         // packed bf16 (y<<16 | x), 40 KB
    __shared__ float    s_intf[HALF_N];     // own half interference, 20 KB
    __shared__ float    red[NWAVES];

    // XCD pairing: both halves of a row land on the same XCD (psi L2 reuse).
    const int bid  = blockIdx.x;
    const int xcd  = bid & 7;
    const int slot = bid >> 3;              // [0,64)
    const int b    = xcd * 32 + (slot >> 1);
    const int half = slot & 1;

    const int t    = threadIdx.x;
    const int lane = t & 63;
    const int wid  = t >> 6;
    const int nbase = half * HALF_N;

    const float lam = lam_p[0];
    const float mu  = mu_p[0];
    const float qx  = query[2*b],  qy = query[2*b+1];
    const float cx  = cur[2*b],    cy = cur[2*b+1];

    const float4* __restrict__ pb4 = (const float4*)(psi + (long)b * NP1 * 2);
    const float2* __restrict__ ab  = (const float2*)(allc + (long)b * NP1 * 2);
    const int4v*  __restrict__ kb  = (const int4v*)(knn + (long)b * NP1 * KNN);
    const int*    __restrict__ mb  = mask + (long)b * NP1;

    // ---- stage FULL psi[b] into LDS (packed bf16), float4 = 2 nodes/lane-iter
    #pragma unroll
    for (int i = 0; i < 5; ++i) {
        const int f = t + i * THREADS;      // float4 index, [0, 5000)
        if (f < NP1 / 2) {
            const float4 p = pb4[f];
            unsigned ux0 = __float_as_uint(p.x);
            unsigned uy0 = __float_as_uint(p.y);
            unsigned ux1 = __float_as_uint(p.z);
            unsigned uy1 = __float_as_uint(p.w);
            ux0 = (ux0 + 0x7FFFu + ((ux0 >> 16) & 1u)) >> 16;          // bf16 RNE
            uy0 = (uy0 + 0x7FFFu + ((uy0 >> 16) & 1u)) & 0xFFFF0000u;
            ux1 = (ux1 + 0x7FFFu + ((ux1 >> 16) & 1u)) >> 16;
            uy1 = (uy1 + 0x7FFFu + ((uy1 >> 16) & 1u)) & 0xFFFF0000u;
            s_psi[2 * f]     = uy0 | ux0;
            s_psi[2 * f + 1] = uy1 | ux1;
        }
    }

    // ---- prefetch own-half per-node data into regs (R7 placement)
    float2 pac[ITEMS_H];
    int    pmk[ITEMS_H];
    #pragma unroll
    for (int i = 0; i < ITEMS_H; ++i) {
        const int ln = t + i * THREADS;
        float2 ac = make_float2(0.f, 0.f);
        int    mk = 0;
        if (ln < HALF_N) {
            ac = ab[nbase + ln];
            mk = mb[nbase + ln];
        }
        pac[i] = ac; pmk[i] = mk;
    }
    __syncthreads();

    // ---- phase A: coalesced knn stream for own half, 8 lanes per node.
    //      knn is read-once -> nontemporal (don't evict psi / raw scores from L2)
    const int gbase = half * GROUPS_H;
    #pragma unroll 2
    for (int g = gbase + wid; g < gbase + GROUPS_H; g += NWAVES) {
        const int4v id = __builtin_nontemporal_load(&kb[(size_t)g * 64 + lane]);
        const int  n0 = g * 8 + (lane >> 3);

        const unsigned up = s_psi[n0];               // 8-lane broadcast
        const float px = __uint_as_float(up << 16);
        const float py = __uint_as_float(up & 0xFFFF0000u);

        const unsigned u0 = s_psi[id.x];
        const unsigned u1 = s_psi[id.y];
        const unsigned u2 = s_psi[id.z];
        const unsigned u3 = s_psi[id.w];
        const float nsx = __uint_as_float(u0 << 16) + __uint_as_float(u1 << 16)
                        + __uint_as_float(u2 << 16) + __uint_as_float(u3 << 16);
        const float nsy = __uint_as_float(u0 & 0xFFFF0000u) + __uint_as_float(u1 & 0xFFFF0000u)
                        + __uint_as_float(u2 & 0xFFFF0000u) + __uint_as_float(u3 & 0xFFFF0000u);

        float dot = px * nsx + py * nsy;             // partial over 4 neighbors
        dot += __shfl_xor(dot, 1);
        dot += __shfl_xor(dot, 2);
        dot += __shfl_xor(dot, 4);                   // sum over all 32 neighbors
        if ((lane & 7) == 0) s_intf[n0 - nbase] = dot;
    }
    __syncthreads();

    // ---- phase B: finish scores for own half (no global loads)
    float sc[ITEMS_H];
    #pragma unroll
    for (int i = 0; i < ITEMS_H; ++i) {
        const int ln = t + i * THREADS;
        float v = -INFINITY;
        if (ln < HALF_N) {
            const unsigned up = s_psi[nbase + ln];
            const float px = __uint_as_float(up << 16);
            const float py = __uint_as_float(up & 0xFFFF0000u);
            const float2 ac = pac[i];
            const float dx = ac.x - cx, dy = ac.y - cy;
            const float dist = sqrtf(dx * dx + dy * dy);
            v = px * qx + py * qy + lam * s_intf[ln] - mu * dist;
            if (pmk[i] != 0) v = NEG_INF;
        }
        sc[i] = v;
    }

    // ---- half-block max
    float m = -INFINITY;
    #pragma unroll
    for (int i = 0; i < ITEMS_H; ++i) m = fmaxf(m, sc[i]);
    #pragma unroll
    for (int off = 32; off > 0; off >>= 1) m = fmaxf(m, __shfl_xor(m, off));
    if (lane == 0) red[wid] = m;
    __syncthreads();
    float M = red[0];
    #pragma unroll
    for (int w = 1; w < NWAVES; ++w) M = fmaxf(M, red[w]);
    __syncthreads();   // red reused below

    // ---- half-block sum of exp(sc - M)
    float s = 0.f;
    #pragma unroll
    for (int i = 0; i < ITEMS_H; ++i) s += __expf(sc[i] - M);
    #pragma unroll
    for (int off = 32; off > 0; off >>= 1) s += __shfl_xor(s, off);
    if (lane == 0) red[wid] = s;
    __syncthreads();
    if (t == 0) {
        float S = 0.f;
        #pragma unroll
        for (int w = 0; w < NWAVES; ++w) S += red[w];
        ws_ms[b * 2 + half] = make_float2(M, S);
    }

    // ---- write raw scores
    #pragma unroll
    for (int i = 0; i < ITEMS_H; ++i) {
        const int ln = t + i * THREADS;
        if (ln < HALF_N) out[(long)b * NP1 + nbase + ln] = sc[i];
    }
}

// ---------------- kernel 2: combine (m,s), subtract lse ----------------
#define CHUNK 2500
__global__ __launch_bounds__(THREADS) void hybrid_finalize_kernel(
    float* __restrict__ out, const float2* __restrict__ ws_ms)
{
    const int bid  = blockIdx.x;
    const int b    = bid >> 2;
    const int cnk  = bid & 3;
    const int t    = threadIdx.x;

    const float2 a = ws_ms[b * 2 + 0];
    const float2 c = ws_ms[b * 2 + 1];
    const float M = fmaxf(a.x, c.x);
    const float S = a.y * __expf(a.x - M) + c.y * __expf(c.x - M);
    const float lse = M + logf(S);

    const long base = (long)b * NP1 + cnk * CHUNK;
    #pragma unroll
    for (int i = 0; i < 3; ++i) {
        const int ln = t + i * THREADS;
        if (ln < CHUNK) out[base + ln] -= lse;
    }
}

extern "C" void kernel_launch(void* const* d_in, const int* in_sizes, int n_in,
                              void* d_out, int out_size, void* d_ws, size_t ws_size,
                              hipStream_t stream) {
    const float* query = (const float*)d_in[0];
    const float* psi   = (const float*)d_in[1];
    const int*   knn   = (const int*)d_in[2];
    const int*   mask  = (const int*)d_in[3];
    const float* cur   = (const float*)d_in[4];
    const float* allc  = (const float*)d_in[5];
    const float* lam   = (const float*)d_in[6];
    const float* mu    = (const float*)d_in[7];
    float* out = (float*)d_out;
    float2* ws_ms = (float2*)d_ws;          // 512 float2 = 4 KB

    hybrid_scores_kernel<<<NB * 2, THREADS, 0, stream>>>(
        query, psi, knn, mask, cur, allc, lam, mu, out, ws_ms);
    hybrid_finalize_kernel<<<NB * 4, THREADS, 0, stream>>>(out, ws_ms);
}

// Round 14
// 68.654 us; speedup vs baseline: 1.3481x; 1.0401x over previous
//
#include <hip/hip_runtime.h>

typedef int   int4v __attribute__((ext_vector_type(4)));
typedef float f2v   __attribute__((ext_vector_type(2)));

#define NB      256
#define NP1     10000
#define KNN     32
#define THREADS 1024
#define NWAVES  (THREADS / 64)
#define HALF_N  (NP1 / 2)        // 5000 nodes per half-block
#define ITEMS_H 5                // per-half items (5000/1024 -> 5)
#define GROUPS_H (HALF_N / 8)    // 625 groups of 8 nodes per half
#define NEG_INF -1000000000.0f

static __device__ __forceinline__ unsigned short bf16_rne(float f) {
    unsigned x = __float_as_uint(f);
    x = (x + 0x7FFFu + ((x >> 16) & 1u)) >> 16;
    return (unsigned short)x;
}

// ---------------- kernel 1: scores (bf16, in-place) + per-half (m, s) ----------------
__global__ __launch_bounds__(THREADS, 8) void hybrid_scores_kernel(
    const float* __restrict__ query,        // [B,2]
    const float* __restrict__ psi,          // [B,NP1,2]
    const int*   __restrict__ knn,          // [B,NP1,K]
    const int*   __restrict__ mask,         // [B,NP1] (bool pushed as int32)
    const float* __restrict__ cur,          // [B,2]
    const float* __restrict__ allc,         // [B,NP1,2]
    const float* __restrict__ lam_p,        // [1]
    const float* __restrict__ mu_p,         // [1]
    float* __restrict__ out,                // [B,NP1]; row prefix used as bf16 scratch
    float2* __restrict__ ws_ms)             // [B*2] per-half (m, s)
{
    __shared__ unsigned s_psi[NP1];         // packed bf16 (y<<16 | x), 40 KB
    __shared__ float    s_intf[HALF_N];     // own half interference, 20 KB
    __shared__ float    red[NWAVES];

    // XCD pairing: both halves of a row land on the same XCD (psi L2 reuse).
    const int bid  = blockIdx.x;
    const int xcd  = bid & 7;
    const int slot = bid >> 3;              // [0,64)
    const int b    = xcd * 32 + (slot >> 1);
    const int half = slot & 1;

    const int t    = threadIdx.x;
    const int lane = t & 63;
    const int wid  = t >> 6;
    const int nbase = half * HALF_N;

    const float lam = lam_p[0];
    const float mu  = mu_p[0];
    const float qx  = query[2*b],  qy = query[2*b+1];
    const float cx  = cur[2*b],    cy = cur[2*b+1];

    const float4* __restrict__ pb4 = (const float4*)(psi + (long)b * NP1 * 2);
    const f2v*    __restrict__ ab  = (const f2v*)(allc + (long)b * NP1 * 2);
    const int4v*  __restrict__ kb  = (const int4v*)(knn + (long)b * NP1 * KNN);
    const int*    __restrict__ mb  = mask + (long)b * NP1;

    // ---- stage FULL psi[b] into LDS (packed bf16), float4 = 2 nodes/lane-iter
    #pragma unroll
    for (int i = 0; i < 5; ++i) {
        const int f = t + i * THREADS;      // float4 index, [0, 5000)
        if (f < NP1 / 2) {
            const float4 p = pb4[f];
            unsigned ux0 = __float_as_uint(p.x);
            unsigned uy0 = __float_as_uint(p.y);
            unsigned ux1 = __float_as_uint(p.z);
            unsigned uy1 = __float_as_uint(p.w);
            ux0 = (ux0 + 0x7FFFu + ((ux0 >> 16) & 1u)) >> 16;          // bf16 RNE
            uy0 = (uy0 + 0x7FFFu + ((uy0 >> 16) & 1u)) & 0xFFFF0000u;
            ux1 = (ux1 + 0x7FFFu + ((ux1 >> 16) & 1u)) >> 16;
            uy1 = (uy1 + 0x7FFFu + ((uy1 >> 16) & 1u)) & 0xFFFF0000u;
            s_psi[2 * f]     = uy0 | ux0;
            s_psi[2 * f + 1] = uy1 | ux1;
        }
    }

    // ---- prefetch own-half per-node data into regs (read-once -> nt)
    f2v pac[ITEMS_H];
    int pmk[ITEMS_H];
    #pragma unroll
    for (int i = 0; i < ITEMS_H; ++i) {
        const int ln = t + i * THREADS;
        f2v ac; ac[0] = 0.f; ac[1] = 0.f;
        int mk = 0;
        if (ln < HALF_N) {
            ac = __builtin_nontemporal_load(&ab[nbase + ln]);
            mk = __builtin_nontemporal_load(&mb[nbase + ln]);
        }
        pac[i] = ac; pmk[i] = mk;
    }
    __syncthreads();

    // ---- phase A: coalesced knn stream for own half, 8 lanes per node.
    //      knn is read-once -> nontemporal (don't evict psi / scores from L2)
    const int gbase = half * GROUPS_H;
    #pragma unroll 2
    for (int g = gbase + wid; g < gbase + GROUPS_H; g += NWAVES) {
        const int4v id = __builtin_nontemporal_load(&kb[(size_t)g * 64 + lane]);
        const int  n0 = g * 8 + (lane >> 3);

        const unsigned up = s_psi[n0];               // 8-lane broadcast
        const float px = __uint_as_float(up << 16);
        const float py = __uint_as_float(up & 0xFFFF0000u);

        const unsigned u0 = s_psi[id.x];
        const unsigned u1 = s_psi[id.y];
        const unsigned u2 = s_psi[id.z];
        const unsigned u3 = s_psi[id.w];
        const float nsx = __uint_as_float(u0 << 16) + __uint_as_float(u1 << 16)
                        + __uint_as_float(u2 << 16) + __uint_as_float(u3 << 16);
        const float nsy = __uint_as_float(u0 & 0xFFFF0000u) + __uint_as_float(u1 & 0xFFFF0000u)
                        + __uint_as_float(u2 & 0xFFFF0000u) + __uint_as_float(u3 & 0xFFFF0000u);

        float dot = px * nsx + py * nsy;             // partial over 4 neighbors
        dot += __shfl_xor(dot, 1);
        dot += __shfl_xor(dot, 2);
        dot += __shfl_xor(dot, 4);                   // sum over all 32 neighbors
        if ((lane & 7) == 0) s_intf[n0 - nbase] = dot;
    }
    __syncthreads();

    // ---- phase B: finish scores for own half (no global loads)
    float sc[ITEMS_H];
    #pragma unroll
    for (int i = 0; i < ITEMS_H; ++i) {
        const int ln = t + i * THREADS;
        float v = -INFINITY;
        if (ln < HALF_N) {
            const unsigned up = s_psi[nbase + ln];
            const float px = __uint_as_float(up << 16);
            const float py = __uint_as_float(up & 0xFFFF0000u);
            const f2v ac = pac[i];
            const float dx = ac[0] - cx, dy = ac[1] - cy;
            const float dist = sqrtf(dx * dx + dy * dy);
            v = px * qx + py * qy + lam * s_intf[ln] - mu * dist;
            if (pmk[i] != 0) v = NEG_INF;
        }
        sc[i] = v;
    }

    // ---- half-block max
    float m = -INFINITY;
    #pragma unroll
    for (int i = 0; i < ITEMS_H; ++i) m = fmaxf(m, sc[i]);
    #pragma unroll
    for (int off = 32; off > 0; off >>= 1) m = fmaxf(m, __shfl_xor(m, off));
    if (lane == 0) red[wid] = m;
    __syncthreads();
    float M = red[0];
    #pragma unroll
    for (int w = 1; w < NWAVES; ++w) M = fmaxf(M, red[w]);
    __syncthreads();   // red reused below

    // ---- half-block sum of exp(sc - M)
    float s = 0.f;
    #pragma unroll
    for (int i = 0; i < ITEMS_H; ++i) s += __expf(sc[i] - M);
    #pragma unroll
    for (int off = 32; off > 0; off >>= 1) s += __shfl_xor(s, off);
    if (lane == 0) red[wid] = s;
    __syncthreads();
    if (t == 0) {
        float S = 0.f;
        #pragma unroll
        for (int w = 0; w < NWAVES; ++w) S += red[w];
        ws_ms[b * 2 + half] = make_float2(M, S);
    }

    // ---- write raw scores as bf16 into this row's out prefix (20 KB/row)
    unsigned short* __restrict__ so = (unsigned short*)(out + (long)b * NP1);
    #pragma unroll
    for (int i = 0; i < ITEMS_H; ++i) {
        const int ln = t + i * THREADS;
        if (ln < HALF_N) so[nbase + ln] = bf16_rne(sc[i]);
    }
}

// ---------------- kernel 2: one block per row; bf16 scores -> f32 log-softmax ----------------
__global__ __launch_bounds__(THREADS) void hybrid_finalize_kernel(
    float* __restrict__ out, const float2* __restrict__ ws_ms)
{
    // XCD-matched to kernel1's row placement: row b was produced on XCD (b>>5)
    const int bid = blockIdx.x;
    const int xcd = bid & 7;
    const int b   = xcd * 32 + (bid >> 3);
    const int t   = threadIdx.x;

    const float2 a = ws_ms[b * 2 + 0];
    const float2 c = ws_ms[b * 2 + 1];
    const float M = fmaxf(a.x, c.x);
    const float S = a.y * __expf(a.x - M) + c.y * __expf(c.x - M);
    const float lse = M + logf(S);

    const unsigned short* __restrict__ so = (const unsigned short*)(out + (long)b * NP1);

    // read all bf16 scores first (they alias the low half of this row's span)
    float v[10];
    #pragma unroll
    for (int i = 0; i < 10; ++i) {
        const int n = t + i * THREADS;
        v[i] = (n < NP1) ? __uint_as_float(((unsigned)so[n]) << 16) : 0.f;
    }
    __syncthreads();   // all reads done before any f32 write lands

    #pragma unroll
    for (int i = 0; i < 10; ++i) {
        const int n = t + i * THREADS;
        if (n < NP1) out[(long)b * NP1 + n] = v[i] - lse;
    }
}

extern "C" void kernel_launch(void* const* d_in, const int* in_sizes, int n_in,
                              void* d_out, int out_size, void* d_ws, size_t ws_size,
                              hipStream_t stream) {
    const float* query = (const float*)d_in[0];
    const float* psi   = (const float*)d_in[1];
    const int*   knn   = (const int*)d_in[2];
    const int*   mask  = (const int*)d_in[3];
    const float* cur   = (const float*)d_in[4];
    const float* allc  = (const float*)d_in[5];
    const float* lam   = (const float*)d_in[6];
    const float* mu    = (const float*)d_in[7];
    float* out = (float*)d_out;
    float2* ws_ms = (float2*)d_ws;          // 512 float2 = 4 KB

    hybrid_scores_kernel<<<NB * 2, THREADS, 0, stream>>>(
        query, psi, knn, mask, cur, allc, lam, mu, out, ws_ms);
    hybrid_finalize_kernel<<<NB, THREADS, 0, stream>>>(out, ws_ms);
}